// Round 15
// baseline (1703.411 us; speedup 1.0000x reference)
//
#include <hip/hip_runtime.h>

#ifndef __has_builtin
#define __has_builtin(x) 0
#endif

__device__ __forceinline__ float fexp2(float x) {
#if __has_builtin(__builtin_amdgcn_exp2f)
  return __builtin_amdgcn_exp2f(x);   // v_exp_f32 (2^x)
#else
  return exp2f(x);
#endif
}
__device__ __forceinline__ float flog2(float x) {
#if __has_builtin(__builtin_amdgcn_logf)
  return __builtin_amdgcn_logf(x);    // v_log_f32 (log2)
#else
  return log2f(x);
#endif
}

typedef float    f32x4 __attribute__((ext_vector_type(4)));
typedef unsigned int u32x2 __attribute__((ext_vector_type(2)));
typedef unsigned int u32x4 __attribute__((ext_vector_type(4)));
typedef _Float16 f16x4 __attribute__((ext_vector_type(4)));

__device__ __forceinline__ f32x4 mfma16x16x16(f16x4 a, f16x4 b, f32x4 c) {
#if __has_builtin(__builtin_amdgcn_mfma_f32_16x16x16_f16)
  return __builtin_amdgcn_mfma_f32_16x16x16_f16(a, b, c, 0, 0, 0);
#else
  return __builtin_amdgcn_mfma_f32_16x16x16f16(a, b, c, 0, 0, 0);
#endif
}

namespace {
constexpr int NPTS = 2048;
constexpr int NPROB = 24;           // 8 batches x {xy, xx, yy}
constexpr int THREADS = 512;        // 8 waves x 16 rows each
constexpr int NPASS = 100;          // 50 Sinkhorn iters x 2 half-passes
constexpr int HALF = 1024;          // sources per WG
constexpr int PH = 512;             // sources per pipeline phase (2 phases)
constexpr float KS  = 1.44269504088896340736f / 0.0025f;   // log2(e)/eps
constexpr float HKS = 0.5f * KS;
constexpr float NEG_EPS_LN2 = -0.0025f * 0.69314718055994530942f; // -eps*ln2
constexpr float LOG2N = 11.0f;                             // log2(2048)
}

// 2-way f16 split: v ~= h + m, residual <= 2^-24|v| (dropped).
__device__ __forceinline__ void split2h(float v, float& h, float& m) {
  h = (float)(_Float16)v;
  m = (float)(_Float16)(v - h);
}
// 3-way f16 split: v == h + m + l EXACTLY (11+11+2 bits cover f32's 24).
__device__ __forceinline__ void split3h(float v, float& h, float& m, float& l) {
  h = (float)(_Float16)v;
  float r1 = v - h;
  m = (float)(_Float16)r1;
  l = r1 - m;
}
// pack two f32 as f16 into one VGPR: a -> k-even (low16), b -> k-odd.
__device__ __forceinline__ unsigned pkh(float a, float b) {
  unsigned short ab = __builtin_bit_cast(unsigned short, (_Float16)a);
  unsigned short bb = __builtin_bit_cast(unsigned short, (_Float16)b);
  return (unsigned)ab | ((unsigned)bb << 16);
}

// One-time prep: per (batch,cloud) point set (16 sets of 2048), precompute the
// pass-invariant source data: packed f16 splits of KS*s (wx,wy,wz) and
// q2 = HKS|s|^2, as one u32x4/source.
__global__ void __launch_bounds__(256) sink_prep(
    const float* __restrict__ p1, const float* __restrict__ p2,
    u32x4* __restrict__ pre)
{
  const int g = blockIdx.x;          // 0..127
  const int set = g >> 3;            // 0..15: 0-7 = p1 batches, 8-15 = p2
  const int j = (g & 7) * 256 + threadIdx.x;
  const float* src = (set < 8) ? p1 + set * (NPTS * 3)
                               : p2 + (set - 8) * (NPTS * 3);
  float sx = src[3 * j + 0], sy = src[3 * j + 1], sz = src[3 * j + 2];
  float q2 = HKS * (sx * sx + sy * sy + sz * sz);
  float shx, smx, shy, smy, shz, smz;
  split2h(KS * sx, shx, smx);
  split2h(KS * sy, shy, smy);
  split2h(KS * sz, shz, smz);
  pre[set * NPTS + j] =
      (u32x4){pkh(shx, smx), pkh(shy, smy), pkh(shz, smz), __float_as_uint(q2)};
}

// MFMA pass (round-15: software-pipelined two-phase staging, T14 pattern).
// WG (p, blk, h): 128 target rows (8 waves x 16), partial LSE over the 1024
// sources of half h, in two 512-source phases with DOUBLE-BUFFERED LDS:
//   stage ph0 -> barrier -> [issue ph1 global loads] -> tiles(ph0)
//   -> ph1 merge-VALU + ds_write -> barrier -> tiles(ph1) -> merge -> store
// Phase-1's HBM/L2 latency and A-merge VALU hide under phase-0's
// trans-saturated tile loop (the ~2 us staging segment that round 14 paid
// serially). LDS 2x16KB+64B -> cap 4 WG/CU >= 3 needed (grid 768, uniform
// single-generation residency, 6 waves/SIMD). 2 barriers/pass.
// Math (round-13-proven two-phase form, absmax 0.0): exp-arg(r,j) =
//   t_r.(KS*s_j) + A_j + B_r - Amax_ph; A_j = KS*phi_j - HKS|s_j|^2;
//   B_r = -HKS|t_r|^2. mfma_f32_16x16x16_f16, 15 slots: kb0/1/2 = x/y/z
//   {th*sh,th*sm,tm*sh,tm*sm}, kb3 = 1*{Ah,Am,Al} (A exact 3-way).
//   Phase merge: wave-uniform factors exp2(Amax_ph - Mx), 2 exps.
// Stored partials (NS=2 contract): m = Mx - B_r, s; LSE_part = m + log2 s + B_r.
template <bool PRE>
__global__ void __launch_bounds__(THREADS, 3) sink_mfma(
    const float* __restrict__ p1, const float* __restrict__ p2,
    float* __restrict__ fm, float* __restrict__ fs,
    float* __restrict__ gm, float* __restrict__ gs,
    const u32x4* __restrict__ pre, int t)
{
  __shared__ u32x4 Bfr[2][PH * 2];  // 2 x 16384 B double buffer
  __shared__ float wmax[2][8];

  const int w   = blockIdx.x;
  const int p   = w >> 5;           // problem 0..23
  const int r_  = w & 31;
  const int blk = r_ & 15;          // row-block (128 rows)
  const int h   = r_ >> 4;          // source half 0/1
  const int b    = p / 3;
  const int kind = p - 3 * b;       // 0: xy, 1: xx, 2: yy
  const float* X = (kind == 2 ? p2 : p1) + b * (NPTS * 3);
  const float* Y = (kind == 1 ? p1 : p2) + b * (NPTS * 3);

  const bool even = (t & 1) == 0;
  const float* tgt = even ? X : Y;
  const float* src = even ? Y : X;
  const int sset = even ? (kind == 1 ? b : 8 + b) : (kind == 2 ? 8 + b : b);
  const u32x4* ps = pre + sset * NPTS;
  const float* pmA = even ? gm : fm;
  const float* psA = even ? gs : fs;
  float* omA = even ? fm : gm;
  float* osA = even ? fs : gs;

  const int tid  = threadIdx.x;
  const int lane = tid & 63;
  const int wv   = tid >> 6;        // wave 0..7
  const int l15  = lane & 15;
  const int kb   = lane >> 4;       // k-block this lane supplies

  // ---- per-lane A-frag: RAW target coords (loads issued first) ----
  const int rowbase = blk * 128 + wv * 16;
  const int r = rowbase + l15;
  float tx = tgt[3 * r + 0], ty = tgt[3 * r + 1], tz = tgt[3 * r + 2];
  float thx, tmx, thy, tmy, thz, tmz;
  split2h(tx, thx, tmx);
  split2h(ty, thy, tmy);
  split2h(tz, thz, tmz);
  u32x2 areg;
  if (kb == 0)      { areg = (u32x2){pkh(thx, thx), pkh(tmx, tmx)}; }
  else if (kb == 1) { areg = (u32x2){pkh(thy, thy), pkh(tmy, tmy)}; }
  else if (kb == 2) { areg = (u32x2){pkh(thz, thz), pkh(tmz, tmz)}; }
  else              { areg = (u32x2){pkh(1.f, 1.f), pkh(1.f, 0.f)}; }
  const f16x4 afrag = __builtin_bit_cast(f16x4, areg);
  const float Bv = -HKS * (tx * tx + ty * ty + tz * tz);
  const float Bq0 = __shfl(Bv, kb * 4 + 0);
  const float Bq1 = __shfl(Bv, kb * 4 + 1);
  const float Bq2 = __shfl(Bv, kb * 4 + 2);
  const float Bq3 = __shfl(Bv, kb * 4 + 3);

  // ---- phase-0 staging: 1 source/thread ----
  const int jl  = tid;
  {
    int jg = HALF * h + jl;
    float A, q2;
    u32x4 pv;
    if constexpr (PRE) {
      pv = ps[jg];
      q2 = __uint_as_float(pv.w);
    } else {
      float sx = src[3 * jg + 0], sy = src[3 * jg + 1], sz = src[3 * jg + 2];
      q2 = HKS * (sx * sx + sy * sy + sz * sz);
      float shx, smx, shy, smy, shz, smz;
      split2h(KS * sx, shx, smx);
      split2h(KS * sy, shy, smy);
      split2h(KS * sz, shz, smz);
      pv = (u32x4){pkh(shx, smx), pkh(shy, smy), pkh(shz, smz), 0u};
    }
    if (t == 0) {
      A = -q2;
    } else {
      float m0 = pmA[(p * 2 + 0) * NPTS + jg];
      float m1 = pmA[(p * 2 + 1) * NPTS + jg];
      float c0 = psA[(p * 2 + 0) * NPTS + jg];
      float c1 = psA[(p * 2 + 1) * NPTS + jg];
      float M = fmaxf(m0, m1);
      float S = fmaf(c0, fexp2(m0 - M), c1 * fexp2(m1 - M));
      A = LOG2N - M - flog2(fmaxf(S, 1e-38f));   // = KS*phi_j - HKS|s_j|^2
    }
    float am = A + q2;               // = KS*phi_j (t==0: exactly 0)
    float Ah, Am_, Al;
    split3h(A, Ah, Am_, Al);         // exact: A == Ah+Am_+Al
    Bfr[0][jl * 2 + 0] = (u32x4){pv.x, pv.x, pv.y, pv.y};
    Bfr[0][jl * 2 + 1] = (u32x4){pv.z, pv.z, pkh(Ah, Am_), pkh(Al, 0.f)};
    #pragma unroll
    for (int off = 1; off <= 32; off <<= 1)
      am = fmaxf(am, __shfl_xor(am, off));
    if (lane == 0) wmax[0][wv] = am;
  }
  __syncthreads();                   // buf0 + wmax0 ready

  // ---- issue phase-1 global loads (latency hides under tiles of ph0) ----
  const int jg1 = HALF * h + PH + jl;
  u32x4 pv1;
  float sx1, sy1, sz1, q21;
  if constexpr (PRE) {
    pv1 = ps[jg1];
    q21 = __uint_as_float(pv1.w);
  } else {
    sx1 = src[3 * jg1 + 0]; sy1 = src[3 * jg1 + 1]; sz1 = src[3 * jg1 + 2];
  }
  float pm0, pm1, pc0, pc1;
  if (t > 0) {
    pm0 = pmA[(p * 2 + 0) * NPTS + jg1];
    pm1 = pmA[(p * 2 + 1) * NPTS + jg1];
    pc0 = psA[(p * 2 + 0) * NPTS + jg1];
    pc1 = psA[(p * 2 + 1) * NPTS + jg1];
  }

  // ---- tiles over buf0 ----
  const float Amax0 =
      fmaxf(fmaxf(fmaxf(wmax[0][0], wmax[0][1]), fmaxf(wmax[0][2], wmax[0][3])),
            fmaxf(fmaxf(wmax[0][4], wmax[0][5]), fmaxf(wmax[0][6], wmax[0][7])));
  float r0 = 0.f, r1 = 0.f, r2 = 0.f, r3 = 0.f;
  {
    const f32x4 cin = {Bq0 - Amax0, Bq1 - Amax0, Bq2 - Amax0, Bq3 - Amax0};
    const u32x2* bptr = (const u32x2*)Bfr[0] + (l15 * 4 + kb);
    #pragma unroll 4
    for (int tile = 0; tile < PH / 16; ++tile) {
      u32x2 braw = *bptr; bptr += 64;
      f16x4 bfrag = __builtin_bit_cast(f16x4, braw);
      f32x4 d = mfma16x16x16(afrag, bfrag, cin);
      r0 += fexp2(d.x);
      r1 += fexp2(d.y);
      r2 += fexp2(d.z);
      r3 += fexp2(d.w);
    }
  }

  // ---- phase-1 staging compute (loads already in flight) ----
  {
    if constexpr (!PRE) {
      q21 = HKS * (sx1 * sx1 + sy1 * sy1 + sz1 * sz1);
      float shx, smx, shy, smy, shz, smz;
      split2h(KS * sx1, shx, smx);
      split2h(KS * sy1, shy, smy);
      split2h(KS * sz1, shz, smz);
      pv1 = (u32x4){pkh(shx, smx), pkh(shy, smy), pkh(shz, smz), 0u};
    }
    float A;
    if (t == 0) {
      A = -q21;
    } else {
      float M = fmaxf(pm0, pm1);
      float S = fmaf(pc0, fexp2(pm0 - M), pc1 * fexp2(pm1 - M));
      A = LOG2N - M - flog2(fmaxf(S, 1e-38f));
    }
    float am = A + q21;
    float Ah, Am_, Al;
    split3h(A, Ah, Am_, Al);
    Bfr[1][jl * 2 + 0] = (u32x4){pv1.x, pv1.x, pv1.y, pv1.y};
    Bfr[1][jl * 2 + 1] = (u32x4){pv1.z, pv1.z, pkh(Ah, Am_), pkh(Al, 0.f)};
    #pragma unroll
    for (int off = 1; off <= 32; off <<= 1)
      am = fmaxf(am, __shfl_xor(am, off));
    if (lane == 0) wmax[1][wv] = am;
  }
  __syncthreads();                   // buf1 + wmax1 ready

  // ---- tiles over buf1 ----
  const float Amax1 =
      fmaxf(fmaxf(fmaxf(wmax[1][0], wmax[1][1]), fmaxf(wmax[1][2], wmax[1][3])),
            fmaxf(fmaxf(wmax[1][4], wmax[1][5]), fmaxf(wmax[1][6], wmax[1][7])));
  float s0 = 0.f, s1 = 0.f, s2 = 0.f, s3 = 0.f;
  {
    const f32x4 cin = {Bq0 - Amax1, Bq1 - Amax1, Bq2 - Amax1, Bq3 - Amax1};
    const u32x2* bptr = (const u32x2*)Bfr[1] + (l15 * 4 + kb);
    #pragma unroll 4
    for (int tile = 0; tile < PH / 16; ++tile) {
      u32x2 braw = *bptr; bptr += 64;
      f16x4 bfrag = __builtin_bit_cast(f16x4, braw);
      f32x4 d = mfma16x16x16(afrag, bfrag, cin);
      s0 += fexp2(d.x);
      s1 += fexp2(d.y);
      s2 += fexp2(d.z);
      s3 += fexp2(d.w);
    }
  }

  // ---- phase merge (wave-uniform factors, 2 exps) ----
  const float Mx = fmaxf(Amax0, Amax1);
  const float f0 = fexp2(Amax0 - Mx);
  const float f1 = fexp2(Amax1 - Mx);
  r0 = fmaf(r0, f0, s0 * f1);
  r1 = fmaf(r1, f0, s1 * f1);
  r2 = fmaf(r2, f0, s2 * f1);
  r3 = fmaf(r3, f0, s3 * f1);

  // ---- reduce across the 16 col-lanes (same m̂ -> pure adds) ----
  #pragma unroll
  for (int off = 1; off <= 8; off <<= 1) {
    r0 += __shfl_xor(r0, off);
    r1 += __shfl_xor(r1, off);
    r2 += __shfl_xor(r2, off);
    r3 += __shfl_xor(r3, off);
  }

  // ---- store partials: m(row kb*4+q) = Mx - B_q ----
  if (l15 == 0) {
    float* om = omA + (p * 2 + h) * NPTS;
    float* os = osA + (p * 2 + h) * NPTS;
    int rr = rowbase + kb * 4;
    om[rr + 0] = Mx - Bq0; os[rr + 0] = r0;
    om[rr + 1] = Mx - Bq1; os[rr + 1] = r1;
    om[rr + 2] = Mx - Bq2; os[rr + 2] = r2;
    om[rr + 3] = Mx - Bq3; os[rr + 3] = r3;
  }
}

// Parallel finalize (round-9-proven, ns=2): 96 WGs x 256, deterministic
// double partials over the 98304 (side,problem,row) values.
__global__ void __launch_bounds__(256) sink_partial(
    const float* __restrict__ fm, const float* __restrict__ fs,
    const float* __restrict__ gm, const float* __restrict__ gs,
    const float* __restrict__ p1, const float* __restrict__ p2,
    double* __restrict__ part)
{
  __shared__ double wsum[4];
  const int tid = threadIdx.x;
  const int blk = blockIdx.x;
  const int PER_SIDE = NPROB * NPTS;     // 49152
  double acc = 0.0;
  #pragma unroll
  for (int k = 0; k < 4; ++k) {
    int idx = blk * 1024 + k * 256 + tid;
    int side = idx >= PER_SIDE;
    int rem  = idx - side * PER_SIDE;
    int p = rem >> 11;
    int i = rem & (NPTS - 1);
    const float* mA = side ? gm : fm;
    const float* sA = side ? gs : fs;
    float m0 = mA[(p * 2 + 0) * NPTS + i], m1 = mA[(p * 2 + 1) * NPTS + i];
    float c0 = sA[(p * 2 + 0) * NPTS + i], c1 = sA[(p * 2 + 1) * NPTS + i];
    float M = fmaxf(m0, m1);
    float S = fmaf(c0, fexp2(m0 - M), c1 * fexp2(m1 - M));
    int b = p / 3, kd = p - 3 * b;
    const float* rows = side ? (kd == 1 ? p1 : p2) : (kd == 2 ? p2 : p1);
    const float* pt = rows + b * (NPTS * 3) + 3 * i;
    float B = -HKS * (pt[0] * pt[0] + pt[1] * pt[1] + pt[2] * pt[2]);
    float val = NEG_EPS_LN2 * (M + B + flog2(fmaxf(S, 1e-38f)) - LOG2N);
    double wgt = (kd == 0) ? 1.0 : -0.5;
    acc += wgt * (double)val;
  }
  #pragma unroll
  for (int off = 1; off <= 32; off <<= 1) acc += __shfl_xor(acc, off);
  if ((tid & 63) == 0) wsum[tid >> 6] = acc;
  __syncthreads();
  if (tid == 0) part[blk] = ((wsum[0] + wsum[1]) + (wsum[2] + wsum[3]));
}

// Stage 2: one wave reduces the 96 partials.
__global__ void __launch_bounds__(64) sink_reduce(
    const double* __restrict__ part, float* __restrict__ out)
{
  const int tid = threadIdx.x;
  double acc = part[tid] + (tid < 32 ? part[64 + tid] : 0.0);
  #pragma unroll
  for (int off = 1; off <= 32; off <<= 1) acc += __shfl_xor(acc, off);
  if (tid == 0) out[0] = (float)(acc / (8.0 * 2048.0));
}

extern "C" void kernel_launch(void* const* d_in, const int* in_sizes, int n_in,
                              void* d_out, int out_size, void* d_ws, size_t ws_size,
                              hipStream_t stream)
{
  const float* p1 = (const float*)d_in[0];   // pcs1 [8,2048,3] f32
  const float* p2 = (const float*)d_in[1];   // pcs2 [8,2048,3] f32
  const size_t elems = (size_t)NPROB * 2 * NPTS;
  float* fm = (float*)d_ws;
  float* fs = fm + elems;
  float* gm = fs + elems;
  float* gs = gm + elems;
  double* part = (double*)(gs + elems);
  u32x4* pre = (u32x4*)(part + 96);
  const size_t need_pre =
      4 * elems * sizeof(float) + 96 * sizeof(double) +
      (size_t)16 * NPTS * sizeof(u32x4);
  const bool use_pre = ws_size >= need_pre;

  if (use_pre) {
    sink_prep<<<dim3(128), dim3(256), 0, stream>>>(p1, p2, pre);
    for (int t = 0; t < NPASS; ++t)
      sink_mfma<true><<<dim3(NPROB * 32), dim3(THREADS), 0, stream>>>(
          p1, p2, fm, fs, gm, gs, pre, t);
  } else {
    for (int t = 0; t < NPASS; ++t)
      sink_mfma<false><<<dim3(NPROB * 32), dim3(THREADS), 0, stream>>>(
          p1, p2, fm, fs, gm, gs, pre, t);
  }
  sink_partial<<<dim3(96), dim3(256), 0, stream>>>(fm, fs, gm, gs, p1, p2, part);
  sink_reduce<<<dim3(1), dim3(64), 0, stream>>>(part, (float*)d_out);
}

// Round 16
// 1645.298 us; speedup vs baseline: 1.0353x; 1.0353x over previous
//
#include <hip/hip_runtime.h>

#ifndef __has_builtin
#define __has_builtin(x) 0
#endif

__device__ __forceinline__ float fexp2(float x) {
#if __has_builtin(__builtin_amdgcn_exp2f)
  return __builtin_amdgcn_exp2f(x);   // v_exp_f32 (2^x)
#else
  return exp2f(x);
#endif
}
__device__ __forceinline__ float flog2(float x) {
#if __has_builtin(__builtin_amdgcn_logf)
  return __builtin_amdgcn_logf(x);    // v_log_f32 (log2)
#else
  return log2f(x);
#endif
}

typedef float    f32x4 __attribute__((ext_vector_type(4)));
typedef unsigned int u32x2 __attribute__((ext_vector_type(2)));
typedef unsigned int u32x4 __attribute__((ext_vector_type(4)));
typedef _Float16 f16x4 __attribute__((ext_vector_type(4)));

__device__ __forceinline__ f32x4 mfma16x16x16(f16x4 a, f16x4 b, f32x4 c) {
#if __has_builtin(__builtin_amdgcn_mfma_f32_16x16x16_f16)
  return __builtin_amdgcn_mfma_f32_16x16x16_f16(a, b, c, 0, 0, 0);
#else
  return __builtin_amdgcn_mfma_f32_16x16x16f16(a, b, c, 0, 0, 0);
#endif
}

namespace {
constexpr int NPTS = 2048;
constexpr int NPROB = 24;           // 8 batches x {xy, xx, yy}
constexpr int THREADS = 512;        // 8 waves x 16 rows each
constexpr int NPASS = 100;          // 50 Sinkhorn iters x 2 half-passes
constexpr int HALF = 1024;          // sources per WG (single phase — round-14)
constexpr float KS  = 1.44269504088896340736f / 0.0025f;   // log2(e)/eps
constexpr float HKS = 0.5f * KS;
constexpr float NEG_EPS_LN2 = -0.0025f * 0.69314718055994530942f; // -eps*ln2
constexpr float LOG2N = 11.0f;                             // log2(2048)
}

// 2-way f16 split: v ~= h + m, residual <= 2^-24|v| (dropped).
__device__ __forceinline__ void split2h(float v, float& h, float& m) {
  h = (float)(_Float16)v;
  m = (float)(_Float16)(v - h);
}
// 3-way f16 split: v == h + m + l EXACTLY (11+11+2 bits cover f32's 24).
__device__ __forceinline__ void split3h(float v, float& h, float& m, float& l) {
  h = (float)(_Float16)v;
  float r1 = v - h;
  m = (float)(_Float16)r1;
  l = r1 - m;
}
// pack two f32 as f16 into one VGPR: a -> k-even (low16), b -> k-odd.
__device__ __forceinline__ unsigned pkh(float a, float b) {
  unsigned short ab = __builtin_bit_cast(unsigned short, (_Float16)a);
  unsigned short bb = __builtin_bit_cast(unsigned short, (_Float16)b);
  return (unsigned)ab | ((unsigned)bb << 16);
}

// One-time prep: per (batch,cloud) point set (16 sets of 2048), precompute the
// pass-invariant source data: packed f16 splits of KS*s (wx,wy,wz) and
// q2 = HKS|s|^2, as one u32x4/source.
__global__ void __launch_bounds__(256) sink_prep(
    const float* __restrict__ p1, const float* __restrict__ p2,
    u32x4* __restrict__ pre)
{
  const int g = blockIdx.x;          // 0..127
  const int set = g >> 3;            // 0..15: 0-7 = p1 batches, 8-15 = p2
  const int j = (g & 7) * 256 + threadIdx.x;
  const float* src = (set < 8) ? p1 + set * (NPTS * 3)
                               : p2 + (set - 8) * (NPTS * 3);
  float sx = src[3 * j + 0], sy = src[3 * j + 1], sz = src[3 * j + 2];
  float q2 = HKS * (sx * sx + sy * sy + sz * sz);
  float shx, smx, shy, smy, shz, smz;
  split2h(KS * sx, shx, smx);
  split2h(KS * sy, shy, smy);
  split2h(KS * sz, shz, smz);
  pre[set * NPTS + j] =
      (u32x4){pkh(shx, smx), pkh(shy, smy), pkh(shz, smz), __float_as_uint(q2)};
}

// MFMA pass (round-14 structure — session best, reinstated after round 15's
// T14 async-pipeline regressed: at 3 WG/CU the staging latency is already
// hidden by cross-WG TLP, so the extra barrier + phase-merge VALU was pure
// cost). WG (p, blk, h): 128 target rows (8 waves x 16), partial LSE over
// ALL 1024 sources of half h, staged once into a 32 KB LDS buffer.
// grid 768 -> 3 WG/CU (LDS cap 4, wave cap 3) -> single-generation
// residency, 6 waves/SIMD. ONE barrier per pass; staging loads (2 src/thread
// + 8 partial floats) issued in one upfront burst.
// Math (round-8/9-proven, bit-compatible): exp-arg(r,j) = t_r.(KS*s_j) + A_j
//   + B_r - Amax; A_j = KS*phi_j - HKS|s_j|^2; B_r = -HKS|t_r|^2;
//   Amax = max over the 1024 staged sources of KS*phi_j.
//   mfma_f32_16x16x16_f16, 15 slots: kb0/1/2 = x/y/z {th*sh,th*sm,tm*sh,
//   tm*sm}, kb3 = 1*{Ah,Am,Al} (A exact 3-way).
// Stored partials (NS=2 contract): m = Amax - B_r, s; LSE_part = m + log2 s + B_r.
template <bool PRE>
__global__ void __launch_bounds__(THREADS, 3) sink_mfma(
    const float* __restrict__ p1, const float* __restrict__ p2,
    float* __restrict__ fm, float* __restrict__ fs,
    float* __restrict__ gm, float* __restrict__ gs,
    const u32x4* __restrict__ pre, int t)
{
  __shared__ u32x4 Bfr[HALF * 2];   // 32768 B: all 1024 sources staged once
  __shared__ float wmax[8];

  const int w   = blockIdx.x;
  const int p   = w >> 5;           // problem 0..23
  const int r_  = w & 31;
  const int blk = r_ & 15;          // row-block (128 rows)
  const int h   = r_ >> 4;          // source half 0/1
  const int b    = p / 3;
  const int kind = p - 3 * b;       // 0: xy, 1: xx, 2: yy
  const float* X = (kind == 2 ? p2 : p1) + b * (NPTS * 3);
  const float* Y = (kind == 1 ? p1 : p2) + b * (NPTS * 3);

  const bool even = (t & 1) == 0;
  const float* tgt = even ? X : Y;
  const float* src = even ? Y : X;
  const int sset = even ? (kind == 1 ? b : 8 + b) : (kind == 2 ? 8 + b : b);
  const u32x4* ps = pre + sset * NPTS;
  const float* pmA = even ? gm : fm;
  const float* psA = even ? gs : fs;
  float* omA = even ? fm : gm;
  float* osA = even ? fs : gs;

  const int tid  = threadIdx.x;
  const int lane = tid & 63;
  const int wv   = tid >> 6;        // wave 0..7
  const int l15  = lane & 15;
  const int kb   = lane >> 4;       // k-block this lane supplies

  // ---- stage all 1024 sources: 2 per thread, loads issued upfront ----
  float am = -1e30f;
  #pragma unroll
  for (int i = 0; i < HALF / THREADS; ++i) {
    int jl = tid + THREADS * i;
    int jg = HALF * h + jl;
    float A, q2;
    u32x4 pv;
    if constexpr (PRE) {
      pv = ps[jg];
      q2 = __uint_as_float(pv.w);
    } else {
      float sx = src[3 * jg + 0], sy = src[3 * jg + 1], sz = src[3 * jg + 2];
      q2 = HKS * (sx * sx + sy * sy + sz * sz);
      float shx, smx, shy, smy, shz, smz;
      split2h(KS * sx, shx, smx);
      split2h(KS * sy, shy, smy);
      split2h(KS * sz, shz, smz);
      pv = (u32x4){pkh(shx, smx), pkh(shy, smy), pkh(shz, smz), 0u};
    }
    if (t == 0) {
      A = -q2;
    } else {
      float m0 = pmA[(p * 2 + 0) * NPTS + jg];
      float m1 = pmA[(p * 2 + 1) * NPTS + jg];
      float c0 = psA[(p * 2 + 0) * NPTS + jg];
      float c1 = psA[(p * 2 + 1) * NPTS + jg];
      float M = fmaxf(m0, m1);
      float S = fmaf(c0, fexp2(m0 - M), c1 * fexp2(m1 - M));
      A = LOG2N - M - flog2(fmaxf(S, 1e-38f));   // = KS*phi_j - HKS|s_j|^2
    }
    am = fmaxf(am, A + q2);          // = KS*phi_j (t==0: exactly 0)
    float Ah, Am_, Al;
    split3h(A, Ah, Am_, Al);         // exact: A == Ah+Am_+Al
    Bfr[jl * 2 + 0] = (u32x4){pv.x, pv.x, pv.y, pv.y};                 // kb0|kb1
    Bfr[jl * 2 + 1] = (u32x4){pv.z, pv.z, pkh(Ah, Am_), pkh(Al, 0.f)}; // kb2|kb3
  }
  #pragma unroll
  for (int off = 1; off <= 32; off <<= 1) am = fmaxf(am, __shfl_xor(am, off));
  if (lane == 0) wmax[wv] = am;

  // ---- per-lane A-frag: RAW target coords, 2-way split ----
  const int rowbase = blk * 128 + wv * 16;
  const int r = rowbase + l15;
  float tx = tgt[3 * r + 0], ty = tgt[3 * r + 1], tz = tgt[3 * r + 2];
  float thx, tmx, thy, tmy, thz, tmz;
  split2h(tx, thx, tmx);
  split2h(ty, thy, tmy);
  split2h(tz, thz, tmz);
  u32x2 areg;
  if (kb == 0)      { areg = (u32x2){pkh(thx, thx), pkh(tmx, tmx)}; }
  else if (kb == 1) { areg = (u32x2){pkh(thy, thy), pkh(tmy, tmy)}; }
  else if (kb == 2) { areg = (u32x2){pkh(thz, thz), pkh(tmz, tmz)}; }
  else              { areg = (u32x2){pkh(1.f, 1.f), pkh(1.f, 0.f)}; }
  const f16x4 afrag = __builtin_bit_cast(f16x4, areg);
  const float Bv = -HKS * (tx * tx + ty * ty + tz * tz);
  const float Bq0 = __shfl(Bv, kb * 4 + 0);
  const float Bq1 = __shfl(Bv, kb * 4 + 1);
  const float Bq2 = __shfl(Bv, kb * 4 + 2);
  const float Bq3 = __shfl(Bv, kb * 4 + 3);

  __syncthreads();                  // the pass's single barrier

  const float Amax =
      fmaxf(fmaxf(fmaxf(wmax[0], wmax[1]), fmaxf(wmax[2], wmax[3])),
            fmaxf(fmaxf(wmax[4], wmax[5]), fmaxf(wmax[6], wmax[7])));
  const f32x4 cin = {Bq0 - Amax, Bq1 - Amax, Bq2 - Amax, Bq3 - Amax};

  // ---- tile loop: 64 tiles of 16 sources; ds_read_b64 per lane ----
  const u32x2* bptr = (const u32x2*)Bfr + (l15 * 4 + kb);
  float r0 = 0.f, r1 = 0.f, r2 = 0.f, r3 = 0.f;
  #pragma unroll 4
  for (int tile = 0; tile < HALF / 16; ++tile) {
    u32x2 braw = *bptr; bptr += 64;    // 16 sources x 4 u32x2 per tile
    f16x4 bfrag = __builtin_bit_cast(f16x4, braw);
    f32x4 d = mfma16x16x16(afrag, bfrag, cin);
    r0 += fexp2(d.x);
    r1 += fexp2(d.y);
    r2 += fexp2(d.z);
    r3 += fexp2(d.w);
  }

  // ---- reduce across the 16 col-lanes (same m̂ -> pure adds) ----
  #pragma unroll
  for (int off = 1; off <= 8; off <<= 1) {
    r0 += __shfl_xor(r0, off);
    r1 += __shfl_xor(r1, off);
    r2 += __shfl_xor(r2, off);
    r3 += __shfl_xor(r3, off);
  }

  // ---- store partials: m(row kb*4+q) = Amax - B_q ----
  if (l15 == 0) {
    float* om = omA + (p * 2 + h) * NPTS;
    float* os = osA + (p * 2 + h) * NPTS;
    int rr = rowbase + kb * 4;
    om[rr + 0] = Amax - Bq0; os[rr + 0] = r0;
    om[rr + 1] = Amax - Bq1; os[rr + 1] = r1;
    om[rr + 2] = Amax - Bq2; os[rr + 2] = r2;
    om[rr + 3] = Amax - Bq3; os[rr + 3] = r3;
  }
}

// Parallel finalize (round-9-proven, ns=2): 96 WGs x 256, deterministic
// double partials over the 98304 (side,problem,row) values.
__global__ void __launch_bounds__(256) sink_partial(
    const float* __restrict__ fm, const float* __restrict__ fs,
    const float* __restrict__ gm, const float* __restrict__ gs,
    const float* __restrict__ p1, const float* __restrict__ p2,
    double* __restrict__ part)
{
  __shared__ double wsum[4];
  const int tid = threadIdx.x;
  const int blk = blockIdx.x;
  const int PER_SIDE = NPROB * NPTS;     // 49152
  double acc = 0.0;
  #pragma unroll
  for (int k = 0; k < 4; ++k) {
    int idx = blk * 1024 + k * 256 + tid;
    int side = idx >= PER_SIDE;
    int rem  = idx - side * PER_SIDE;
    int p = rem >> 11;
    int i = rem & (NPTS - 1);
    const float* mA = side ? gm : fm;
    const float* sA = side ? gs : fs;
    float m0 = mA[(p * 2 + 0) * NPTS + i], m1 = mA[(p * 2 + 1) * NPTS + i];
    float c0 = sA[(p * 2 + 0) * NPTS + i], c1 = sA[(p * 2 + 1) * NPTS + i];
    float M = fmaxf(m0, m1);
    float S = fmaf(c0, fexp2(m0 - M), c1 * fexp2(m1 - M));
    int b = p / 3, kd = p - 3 * b;
    const float* rows = side ? (kd == 1 ? p1 : p2) : (kd == 2 ? p2 : p1);
    const float* pt = rows + b * (NPTS * 3) + 3 * i;
    float B = -HKS * (pt[0] * pt[0] + pt[1] * pt[1] + pt[2] * pt[2]);
    float val = NEG_EPS_LN2 * (M + B + flog2(fmaxf(S, 1e-38f)) - LOG2N);
    double wgt = (kd == 0) ? 1.0 : -0.5;
    acc += wgt * (double)val;
  }
  #pragma unroll
  for (int off = 1; off <= 32; off <<= 1) acc += __shfl_xor(acc, off);
  if ((tid & 63) == 0) wsum[tid >> 6] = acc;
  __syncthreads();
  if (tid == 0) part[blk] = ((wsum[0] + wsum[1]) + (wsum[2] + wsum[3]));
}

// Stage 2: one wave reduces the 96 partials.
__global__ void __launch_bounds__(64) sink_reduce(
    const double* __restrict__ part, float* __restrict__ out)
{
  const int tid = threadIdx.x;
  double acc = part[tid] + (tid < 32 ? part[64 + tid] : 0.0);
  #pragma unroll
  for (int off = 1; off <= 32; off <<= 1) acc += __shfl_xor(acc, off);
  if (tid == 0) out[0] = (float)(acc / (8.0 * 2048.0));
}

extern "C" void kernel_launch(void* const* d_in, const int* in_sizes, int n_in,
                              void* d_out, int out_size, void* d_ws, size_t ws_size,
                              hipStream_t stream)
{
  const float* p1 = (const float*)d_in[0];   // pcs1 [8,2048,3] f32
  const float* p2 = (const float*)d_in[1];   // pcs2 [8,2048,3] f32
  const size_t elems = (size_t)NPROB * 2 * NPTS;
  float* fm = (float*)d_ws;
  float* fs = fm + elems;
  float* gm = fs + elems;
  float* gs = gm + elems;
  double* part = (double*)(gs + elems);
  u32x4* pre = (u32x4*)(part + 96);
  const size_t need_pre =
      4 * elems * sizeof(float) + 96 * sizeof(double) +
      (size_t)16 * NPTS * sizeof(u32x4);
  const bool use_pre = ws_size >= need_pre;

  if (use_pre) {
    sink_prep<<<dim3(128), dim3(256), 0, stream>>>(p1, p2, pre);
    for (int t = 0; t < NPASS; ++t)
      sink_mfma<true><<<dim3(NPROB * 32), dim3(THREADS), 0, stream>>>(
          p1, p2, fm, fs, gm, gs, pre, t);
  } else {
    for (int t = 0; t < NPASS; ++t)
      sink_mfma<false><<<dim3(NPROB * 32), dim3(THREADS), 0, stream>>>(
          p1, p2, fm, fs, gm, gs, pre, t);
  }
  sink_partial<<<dim3(96), dim3(256), 0, stream>>>(fm, fs, gm, gs, p1, p2, part);
  sink_reduce<<<dim3(1), dim3(64), 0, stream>>>(part, (float*)d_out);
}